// Round 14
// baseline (62.953 us; speedup 1.0000x reference)
//
#include <hip/hip_runtime.h>

#define B_ 32
#define Q_ 16
#define D_ 2048
#define E_ 300
#define EF4 75              // float4 granules per embedding row
#define NB 30
#define TR 64               // doc rows per block (lane = row)
#define PITCH 75            // LDS granules per row (stride 300 dw spreads quad-starts)
#define TPB (D_ / TR)       // 32 tiles per batch

// Hardware-TRANS-pipe transcendentals (R2: ocml tanhf/log1pf left final 99% stalled)
__device__ __forceinline__ float fast_tanh(float x) {
    const float t = __expf(-2.0f * fabsf(x));
    const float r = (1.0f - t) / (1.0f + t);
    return copysignf(r, x);
}
__device__ __forceinline__ float fast_log1p(float x) { return __logf(1.0f + x); }

// async global->LDS, 16B per lane (m97 lever: no VGPR round trip)
__device__ __forceinline__ void gload_lds16(const float4* g, float4* l) {
    __builtin_amdgcn_global_load_lds(
        (const __attribute__((address_space(1))) void*)g,
        (__attribute__((address_space(3))) void*)l, 16, 0, 0);
}

// ---------------- Kernel 1: query prep (qn, gate logits) + hist zero ----------------
__global__ __launch_bounds__(256) void drmm_prep(
    const int* __restrict__ query, const float* __restrict__ emb,
    const float* __restrict__ Wg, const float* __restrict__ bg,
    float* __restrict__ qn, float* __restrict__ gbuf, int* __restrict__ hist)
{
    const int b = blockIdx.x, tid = threadIdx.x;
    const int wid = tid >> 6, lane = tid & 63;

    for (int i = b * 256 + tid; i < B_ * Q_ * NB; i += B_ * 256) hist[i] = 0;

    for (int qq = wid; qq < Q_; qq += 4) {
        const int id = query[b * Q_ + qq];
        const float m = (id > 0) ? 1.f : 0.f;
        const float* row = emb + (long long)((id > 0) ? id : 0) * E_;
        float v[5];
        float ss = 0.f, dg = 0.f;
        #pragma unroll
        for (int k = 0; k < 5; ++k) {
            const int e = lane + 64 * k;
            float x = 0.f, w = 0.f;
            if (e < E_) { x = row[e] * m; w = Wg[e]; }
            v[k] = x;
            ss = fmaf(x, x, ss);
            dg = fmaf(x, w, dg);
        }
        #pragma unroll
        for (int off = 32; off > 0; off >>= 1) {
            ss += __shfl_xor(ss, off);
            dg += __shfl_xor(dg, off);
        }
        // masked row: ss==0 -> rn=inf -> qn = 0*inf = NaN (matches reference 0/0)
        const float rn = 1.0f / sqrtf(ss);
        #pragma unroll
        for (int k = 0; k < 5; ++k) {
            const int e = lane + 64 * k;
            if (e < E_) qn[((size_t)(b * Q_ + qq)) * E_ + e] = v[k] * rn;
        }
        if (lane == 0) gbuf[b * Q_ + qq] = fast_tanh(dg + bg[0]);
    }
}

// ---------------- Kernel 2: interaction dots + histogram ----------------
// R13 post-mortem: q via SMEM s_load serialized the inner loop — SMEM retires
// OUT-OF-ORDER, so every consume forces s_waitcnt lgkmcnt(0), draining all
// outstanding scalar loads; ~150cy exposed per 3-iter window (R4 and R13 both
// ~40-46us with scalar q-loads; VALUBusy only 16%). Fix: launder the per-wave
// q base pointer through LDS (qsp[w]) so the compiler CANNOT prove it uniform
// -> q loads become VMEM global_load_dwordx4 (vmcnt, IN-ORDER, auto-pipelined;
// 64-lane same-address = one broadcast L2 request per load). Also: staging row
// ids via ONE vector load + readlane instead of 16 serial s_load chains.
__global__ __launch_bounds__(256, 2) void drmm_main(
    const int* __restrict__ doc, const float* __restrict__ emb,
    const float* __restrict__ qn, int* __restrict__ hist)
{
    __shared__ __align__(16) float4 ds[TR * PITCH];   // 76800 B
    __shared__ int whist[Q_ * NB];                    // 1920 B
    __shared__ const float4* qsp[4];                  // laundered q base ptrs

    const int tid = threadIdx.x;
    // XCD-grouped decode: xcd = blk&7 hosts batches {xcd, 8+xcd, 16+xcd, 24+xcd}
    const int blk = blockIdx.x;                       // 0..1023
    const int xcd = blk & 7;
    const int j   = blk >> 3;                         // 0..127
    const int b   = ((j & 3) << 3) | xcd;             // 0..31
    const int tile = j >> 2;                          // 0..31
    const int lane = tid & 63;
    const int w = __builtin_amdgcn_readfirstlane(tid >> 6);

    for (int i = tid; i < Q_ * NB; i += 256) whist[i] = 0;
    if (tid < 4)
        qsp[tid] = (const float4*)(qn + (size_t)b * Q_ * E_ + (size_t)(tid * 4) * E_);

    const int rowbase = b * D_ + tile * TR;
    const int myrid = doc[rowbase + lane];            // one VMEM load: 64 row ids

    // stage 64 rows (16 per wave), async DMA; rid via readlane (no serial s_loads)
    #pragma unroll
    for (int i = 0; i < 16; ++i) {
        const int r = w * 16 + i;
        int rid = __builtin_amdgcn_readlane(myrid, r);
        rid = rid > 0 ? rid : 0;
        const float4* g4 = (const float4*)(emb + (long long)rid * E_);
        gload_lds16(g4 + lane, &ds[r * PITCH]);                    // granules 0-63
        if (lane < EF4 - 64) gload_lds16(g4 + 64 + lane, &ds[r * PITCH + 64]); // 64-74
    }
    __syncthreads();    // drains the DMA; other resident block computes meanwhile

    // compute: lane = row; wave w owns q 4w..4w+3; q loads via laundered VGPR
    // pointer -> VMEM, pipelined by the compiler across the unroll-3 window.
    const float4* drow = ds + lane * PITCH;
    const float4* qw = qsp[w];                        // ds_read -> divergent-typed

    float a0 = 0.f, a1 = 0.f, a2 = 0.f, a3 = 0.f, ss = 0.f;
    #pragma unroll 3
    for (int k = 0; k < EF4; ++k) {
        const float4 d = drow[k];                     // the one DS read
        const float4 u0 = qw[0 * EF4 + k];            // VMEM broadcast loads
        const float4 u1 = qw[1 * EF4 + k];
        const float4 u2 = qw[2 * EF4 + k];
        const float4 u3 = qw[3 * EF4 + k];
        ss = fmaf(d.x, d.x, fmaf(d.y, d.y, fmaf(d.z, d.z, fmaf(d.w, d.w, ss))));
        a0 = fmaf(d.x,u0.x, fmaf(d.y,u0.y, fmaf(d.z,u0.z, fmaf(d.w,u0.w, a0))));
        a1 = fmaf(d.x,u1.x, fmaf(d.y,u1.y, fmaf(d.z,u1.z, fmaf(d.w,u1.w, a1))));
        a2 = fmaf(d.x,u2.x, fmaf(d.y,u2.y, fmaf(d.z,u2.z, fmaf(d.w,u2.w, a2))));
        a3 = fmaf(d.x,u3.x, fmaf(d.y,u3.y, fmaf(d.z,u3.z, fmaf(d.w,u3.w, a3))));
    }

    const float rn = 1.0f / sqrtf(ss);   // ss==0 -> inf -> NaN sims -> dropped
    const bool rok = (myrid > 0);
    const int qb = w * 4;
    #define BIN1(X, QI) { const float x_ = (X); \
        const float t_ = (x_ + 1.0f) * (NB * 0.5f); \
        int bin_ = (int)floorf(t_); \
        bin_ = bin_ < 0 ? 0 : (bin_ > NB - 1 ? NB - 1 : bin_); \
        if (rok && x_ >= -1.0f && x_ <= 1.0f) atomicAdd(&whist[(QI) * NB + bin_], 1); }
    BIN1(a0 * rn, qb + 0)
    BIN1(a1 * rn, qb + 1)
    BIN1(a2 * rn, qb + 2)
    BIN1(a3 * rn, qb + 3)
    #undef BIN1
    __syncthreads();

    // flush block histogram to global
    for (int i = tid; i < Q_ * NB; i += 256) {
        const int v = whist[i];
        if (v) atomicAdd(&hist[b * Q_ * NB + i], v);
    }
}

// ---------------- Kernel 3: log1p + FFN + gated sum ----------------
__global__ __launch_bounds__(64) void drmm_final(
    const int* __restrict__ hist, const float* __restrict__ gbuf,
    const int* __restrict__ query,
    const float* __restrict__ W1, const float* __restrict__ b1,
    const float* __restrict__ W2, const float* __restrict__ b2,
    const float* __restrict__ W3, const float* __restrict__ b3,
    float* __restrict__ out)
{
    const int b = blockIdx.x, lane = threadIdx.x;
    float z = 0.f, e = 0.f;
    if (lane < Q_) {
        const int* h = hist + (b * Q_ + lane) * NB;
        float pre1[5];
        #pragma unroll
        for (int u = 0; u < 5; ++u) pre1[u] = b1[u];
        #pragma unroll
        for (int k = 0; k < NB; ++k) {
            const float hv = fast_log1p((float)h[k]);
            #pragma unroll
            for (int u = 0; u < 5; ++u) pre1[u] = fmaf(hv, W1[k * 5 + u], pre1[u]);
        }
        float z2 = b2[0];
        #pragma unroll
        for (int u = 0; u < 5; ++u) z2 = fmaf(fast_tanh(pre1[u]), W2[u], z2);
        const float z3 = fmaf(fast_tanh(z2), W3[0], b3[0]);
        z = fast_tanh(z3);
        const int id = query[b * Q_ + lane];
        const float g = gbuf[b * Q_ + lane];
        e = (id > 0) ? __expf(g) : 0.f;
    }
    float ze = z * e, se = e;
    #pragma unroll
    for (int off = 32; off > 0; off >>= 1) {
        ze += __shfl_xor(ze, off);
        se += __shfl_xor(se, off);
    }
    if (lane == 0) out[b] = ze / (se + 1e-5f);
}

// ---------------- launch ----------------
extern "C" void kernel_launch(void* const* d_in, const int* in_sizes, int n_in,
                              void* d_out, int out_size, void* d_ws, size_t ws_size,
                              hipStream_t stream)
{
    const int*   query = (const int*)d_in[0];
    const int*   doc   = (const int*)d_in[1];
    // d_in[2] = q_idf (unused by reference)
    const float* emb   = (const float*)d_in[3];
    const float* W1    = (const float*)d_in[4];
    const float* b1    = (const float*)d_in[5];
    const float* W2    = (const float*)d_in[6];
    const float* b2    = (const float*)d_in[7];
    const float* W3    = (const float*)d_in[8];
    const float* b3    = (const float*)d_in[9];
    const float* Wg    = (const float*)d_in[10];
    const float* bg    = (const float*)d_in[11];
    float* out = (float*)d_out;

    // workspace layout
    char* ws = (char*)d_ws;
    float* qn   = (float*)ws;                        // 512*300 f32 = 614400 B
    float* gbuf = (float*)(ws + 614400);             // 512 f32    = 2048 B
    int*   hist = (int*)(ws + 614400 + 2048);        // 15360 ints = 61440 B

    drmm_prep<<<B_, 256, 0, stream>>>(query, emb, Wg, bg, qn, gbuf, hist);
    drmm_main<<<B_ * TPB, 256, 0, stream>>>(doc, emb, qn, hist);
    drmm_final<<<B_, 64, 0, stream>>>(hist, gbuf, query,
                                      W1, b1, W2, b2, W3, b3, out);
}